// Round 1
// baseline (2960.324 us; speedup 1.0000x reference)
//
#include <hip/hip_runtime.h>
#include <hip/hip_bf16.h>
#include <math.h>

#define N_NODES 100000
#define N_EDGES 1600000
#define N_GRAPHS 1024

// ---------------- layer 1: node linear (128 -> 64) x4 matrices ----------------
// one block (256 thr) per node: threads 0-63 -> q, 64-127 -> k, 128-191 -> v, 192-255 -> skip
__global__ void node_lin1(const float* __restrict__ x,
                          const float* __restrict__ Wq, const float* __restrict__ bq,
                          const float* __restrict__ Wk, const float* __restrict__ bk,
                          const float* __restrict__ Wv, const float* __restrict__ bv,
                          const float* __restrict__ Ws, const float* __restrict__ bs,
                          float* __restrict__ q, float* __restrict__ k,
                          float* __restrict__ v, float* __restrict__ s) {
    int n = blockIdx.x;
    __shared__ float xs[128];
    int t = threadIdx.x;
    if (t < 128) xs[t] = x[(size_t)n * 128 + t];
    __syncthreads();
    int c = t & 63;
    int which = t >> 6;
    const float* W = (which == 0) ? Wq : (which == 1) ? Wk : (which == 2) ? Wv : Ws;
    const float* b = (which == 0) ? bq : (which == 1) ? bk : (which == 2) ? bv : bs;
    float acc = 0.f;
#pragma unroll 16
    for (int j = 0; j < 128; ++j) acc += xs[j] * W[j * 64 + c];
    acc += b[c];
    float* out = (which == 0) ? q : (which == 1) ? k : (which == 2) ? v : s;
    out[(size_t)n * 64 + c] = acc;
}

// ---------------- layer 1: edge scores (64 lanes per edge) ----------------
__global__ void edge_score1(const float* __restrict__ ea, const int* __restrict__ ei,
                            const float* __restrict__ q, const float* __restrict__ k,
                            const float* __restrict__ We,
                            float* __restrict__ sc, unsigned* __restrict__ mmax) {
    int gid = blockIdx.x * blockDim.x + threadIdx.x;
    int e = gid >> 6;
    int t = threadIdx.x & 63;
    if (e >= N_EDGES) return;
    int src = ei[e];
    int dst = ei[N_EDGES + e];
    const float* eap = ea + (size_t)e * 32;
    float ev = 0.f;
#pragma unroll
    for (int j = 0; j < 32; ++j) ev += eap[j] * We[j * 64 + t];
    float ke = k[(size_t)src * 64 + t] + ev;
    float p = q[(size_t)dst * 64 + t] * ke;
#pragma unroll
    for (int m = 32; m > 0; m >>= 1) p += __shfl_xor(p, m, 64);
    if (t == 0) {
        float score = p * 0.125f;  // / sqrt(64)
        sc[e] = score;
        unsigned bits = __float_as_uint(score);
        unsigned enc = (bits & 0x80000000u) ? ~bits : (bits | 0x80000000u);
        atomicMax(mmax + dst, enc);
    }
}

// ---------------- exp + denominator (1 thread per edge) ----------------
__global__ void edge_exp(const int* __restrict__ ei, const unsigned* __restrict__ mmax,
                         float* __restrict__ sc, float* __restrict__ den) {
    int e = blockIdx.x * blockDim.x + threadIdx.x;
    if (e >= N_EDGES) return;
    int dst = ei[N_EDGES + e];
    unsigned u = mmax[dst];
    unsigned bits = (u & 0x80000000u) ? (u ^ 0x80000000u) : ~u;
    float m = __uint_as_float(bits);
    float a = expf(sc[e] - m);
    sc[e] = a;
    atomicAdd(den + dst, a);
}

// ---------------- layer 1: aggregate (64 lanes per edge) ----------------
__global__ void edge_agg1(const float* __restrict__ ea, const int* __restrict__ ei,
                          const float* __restrict__ v, const float* __restrict__ We,
                          const float* __restrict__ sc, const float* __restrict__ den,
                          float* __restrict__ agg) {
    int gid = blockIdx.x * blockDim.x + threadIdx.x;
    int e = gid >> 6;
    int t = threadIdx.x & 63;
    if (e >= N_EDGES) return;
    int src = ei[e];
    int dst = ei[N_EDGES + e];
    float alpha = sc[e] / (den[dst] + 1e-16f);
    const float* eap = ea + (size_t)e * 32;
    float ev = 0.f;
#pragma unroll
    for (int j = 0; j < 32; ++j) ev += eap[j] * We[j * 64 + t];
    float ve = v[(size_t)src * 64 + t] + ev;
    atomicAdd(agg + (size_t)dst * 64 + t, alpha * ve);
}

// ---------------- relu(agg + skip) -> write into skip buffer ----------------
__global__ void relu_add(const float* __restrict__ agg, float* __restrict__ s, int n) {
    int i = blockIdx.x * blockDim.x + threadIdx.x;
    if (i < n) {
        float r = agg[i] + s[i];
        s[i] = r > 0.f ? r : 0.f;
    }
}

// ---------------- layer 2: node linear (64 -> 16) x4 ----------------
// block 256 = 4 nodes; per node 64 threads: which = (t&63)>>4, c = t&15
__global__ void node_lin2(const float* __restrict__ h,
                          const float* __restrict__ Wq, const float* __restrict__ bq,
                          const float* __restrict__ Wk, const float* __restrict__ bk,
                          const float* __restrict__ Wv, const float* __restrict__ bv,
                          const float* __restrict__ Ws, const float* __restrict__ bs,
                          float* __restrict__ q, float* __restrict__ k,
                          float* __restrict__ v, float* __restrict__ s) {
    int t = threadIdx.x;
    int ln = t >> 6;                     // local node 0..3
    int n = blockIdx.x * 4 + ln;
    __shared__ float hs[4][64];
    if (n < N_NODES) hs[ln][t & 63] = h[(size_t)n * 64 + (t & 63)];
    __syncthreads();
    if (n >= N_NODES) return;
    int tt = t & 63;
    int which = tt >> 4;
    int c = tt & 15;
    const float* W = (which == 0) ? Wq : (which == 1) ? Wk : (which == 2) ? Wv : Ws;
    const float* b = (which == 0) ? bq : (which == 1) ? bk : (which == 2) ? bv : bs;
    float acc = 0.f;
#pragma unroll 16
    for (int j = 0; j < 64; ++j) acc += hs[ln][j] * W[j * 16 + c];
    acc += b[c];
    float* out = (which == 0) ? q : (which == 1) ? k : (which == 2) ? v : s;
    out[(size_t)n * 16 + c] = acc;
}

// ---------------- layer 2: edge scores (16 lanes per edge) ----------------
__global__ void edge_score2(const float* __restrict__ ea, const int* __restrict__ ei,
                            const float* __restrict__ q, const float* __restrict__ k,
                            const float* __restrict__ We,
                            float* __restrict__ sc, unsigned* __restrict__ mmax) {
    int gid = blockIdx.x * blockDim.x + threadIdx.x;
    int e = gid >> 4;
    int t = threadIdx.x & 15;
    if (e >= N_EDGES) return;
    int src = ei[e];
    int dst = ei[N_EDGES + e];
    const float* eap = ea + (size_t)e * 32;
    float ev = 0.f;
#pragma unroll
    for (int j = 0; j < 32; ++j) ev += eap[j] * We[j * 16 + t];
    float ke = k[(size_t)src * 16 + t] + ev;
    float p = q[(size_t)dst * 16 + t] * ke;
#pragma unroll
    for (int m = 8; m > 0; m >>= 1) p += __shfl_xor(p, m, 16);
    if (t == 0) {
        float score = p * 0.25f;  // / sqrt(16)
        sc[e] = score;
        unsigned bits = __float_as_uint(score);
        unsigned enc = (bits & 0x80000000u) ? ~bits : (bits | 0x80000000u);
        atomicMax(mmax + dst, enc);
    }
}

// ---------------- layer 2: aggregate (16 lanes per edge) ----------------
__global__ void edge_agg2(const float* __restrict__ ea, const int* __restrict__ ei,
                          const float* __restrict__ v, const float* __restrict__ We,
                          const float* __restrict__ sc, const float* __restrict__ den,
                          float* __restrict__ agg) {
    int gid = blockIdx.x * blockDim.x + threadIdx.x;
    int e = gid >> 4;
    int t = threadIdx.x & 15;
    if (e >= N_EDGES) return;
    int src = ei[e];
    int dst = ei[N_EDGES + e];
    float alpha = sc[e] / (den[dst] + 1e-16f);
    const float* eap = ea + (size_t)e * 32;
    float ev = 0.f;
#pragma unroll
    for (int j = 0; j < 32; ++j) ev += eap[j] * We[j * 16 + t];
    float ve = v[(size_t)src * 16 + t] + ev;
    atomicAdd(agg + (size_t)dst * 16 + t, alpha * ve);
}

// ---------------- pool: atomic sums per graph ----------------
__global__ void pool_sum(const float* __restrict__ h2, const int* __restrict__ batch,
                         float* __restrict__ sums, float* __restrict__ cnt) {
    int idx = blockIdx.x * blockDim.x + threadIdx.x;
    if (idx >= N_NODES * 16) return;
    int n = idx >> 4;
    int c = idx & 15;
    int g = batch[n];
    atomicAdd(sums + g * 16 + c, h2[idx]);
    if (c == 0) atomicAdd(cnt + g, 1.0f);
}

// ---------------- final fc + sigmoid ----------------
__global__ void final_fc(const float* __restrict__ sums, const float* __restrict__ cnt,
                         const float* __restrict__ Wf, const float* __restrict__ bf,
                         float* __restrict__ out) {
    int g = blockIdx.x * blockDim.x + threadIdx.x;
    if (g >= N_GRAPHS) return;
    float cc = cnt[g];
    cc = cc > 1.f ? cc : 1.f;
    float acc = bf[0];
#pragma unroll
    for (int c = 0; c < 16; ++c) acc += (sums[g * 16 + c] / cc) * Wf[c];
    out[g] = 1.f / (1.f + expf(-acc));
}

extern "C" void kernel_launch(void* const* d_in, const int* in_sizes, int n_in,
                              void* d_out, int out_size, void* d_ws, size_t ws_size,
                              hipStream_t stream) {
    const float* x    = (const float*)d_in[0];
    const float* ea   = (const float*)d_in[1];
    const float* Wq1  = (const float*)d_in[2];
    const float* bq1  = (const float*)d_in[3];
    const float* Wk1  = (const float*)d_in[4];
    const float* bk1  = (const float*)d_in[5];
    const float* Wv1  = (const float*)d_in[6];
    const float* bv1  = (const float*)d_in[7];
    const float* We1  = (const float*)d_in[8];
    const float* Ws1  = (const float*)d_in[9];
    const float* bs1  = (const float*)d_in[10];
    const float* Wq2  = (const float*)d_in[11];
    const float* bq2  = (const float*)d_in[12];
    const float* Wk2  = (const float*)d_in[13];
    const float* bk2  = (const float*)d_in[14];
    const float* Wv2  = (const float*)d_in[15];
    const float* bv2  = (const float*)d_in[16];
    const float* We2  = (const float*)d_in[17];
    const float* Ws2  = (const float*)d_in[18];
    const float* bs2  = (const float*)d_in[19];
    const float* Wf   = (const float*)d_in[20];
    const float* bf   = (const float*)d_in[21];
    const int*   ei   = (const int*)d_in[22];
    const int*   batch= (const int*)d_in[23];
    float* out = (float*)d_out;

    // workspace layout (floats)
    float* ws = (float*)d_ws;
    size_t off = 0;
    float* q1   = ws + off; off += (size_t)N_NODES * 64;
    float* k1   = ws + off; off += (size_t)N_NODES * 64;
    float* v1   = ws + off; off += (size_t)N_NODES * 64;
    float* s1   = ws + off; off += (size_t)N_NODES * 64;   // skip; becomes h1 after relu_add
    // ---- zero block 1: agg1, m1, den1 (contiguous) ----
    float* zero1 = ws + off;
    float* agg1 = ws + off; off += (size_t)N_NODES * 64;
    float* m1   = ws + off; off += N_NODES;                 // encoded-uint max
    float* den1 = ws + off; off += N_NODES;
    size_t zero1_bytes = (size_t)(N_NODES * 64 + 2 * N_NODES) * sizeof(float);
    float* sc   = ws + off; off += N_EDGES;                 // scores, then a
    float* q2   = ws + off; off += (size_t)N_NODES * 16;
    float* k2   = ws + off; off += (size_t)N_NODES * 16;
    float* v2   = ws + off; off += (size_t)N_NODES * 16;
    float* s2   = ws + off; off += (size_t)N_NODES * 16;    // skip; becomes h2
    // ---- zero block 2: agg2, m2, den2, sums, cnt (contiguous) ----
    float* zero2 = ws + off;
    float* agg2 = ws + off; off += (size_t)N_NODES * 16;
    float* m2   = ws + off; off += N_NODES;
    float* den2 = ws + off; off += N_NODES;
    float* sums = ws + off; off += (size_t)N_GRAPHS * 16;
    float* cnt  = ws + off; off += N_GRAPHS;
    size_t zero2_bytes = ((size_t)N_NODES * 16 + 2 * N_NODES + N_GRAPHS * 16 + N_GRAPHS) * sizeof(float);

    hipMemsetAsync(zero1, 0, zero1_bytes, stream);
    hipMemsetAsync(zero2, 0, zero2_bytes, stream);

    // ---- layer 1 ----
    node_lin1<<<N_NODES, 256, 0, stream>>>(x, Wq1, bq1, Wk1, bk1, Wv1, bv1, Ws1, bs1,
                                           q1, k1, v1, s1);
    {
        int blocks = (N_EDGES * 64 + 255) / 256;
        edge_score1<<<blocks, 256, 0, stream>>>(ea, ei, q1, k1, We1, sc, (unsigned*)m1);
    }
    edge_exp<<<(N_EDGES + 255) / 256, 256, 0, stream>>>(ei, (const unsigned*)m1, sc, den1);
    {
        int blocks = (N_EDGES * 64 + 255) / 256;
        edge_agg1<<<blocks, 256, 0, stream>>>(ea, ei, v1, We1, sc, den1, agg1);
    }
    relu_add<<<(N_NODES * 64 + 255) / 256, 256, 0, stream>>>(agg1, s1, N_NODES * 64);

    // ---- layer 2 (input h1 = s1) ----
    node_lin2<<<(N_NODES + 3) / 4, 256, 0, stream>>>(s1, Wq2, bq2, Wk2, bk2, Wv2, bv2, Ws2, bs2,
                                                     q2, k2, v2, s2);
    {
        int blocks = (N_EDGES * 16 + 255) / 256;
        edge_score2<<<blocks, 256, 0, stream>>>(ea, ei, q2, k2, We2, sc, (unsigned*)m2);
    }
    edge_exp<<<(N_EDGES + 255) / 256, 256, 0, stream>>>(ei, (const unsigned*)m2, sc, den2);
    {
        int blocks = (N_EDGES * 16 + 255) / 256;
        edge_agg2<<<blocks, 256, 0, stream>>>(ea, ei, v2, We2, sc, den2, agg2);
    }
    relu_add<<<(N_NODES * 16 + 255) / 256, 256, 0, stream>>>(agg2, s2, N_NODES * 16);

    // ---- pool + fc ----
    pool_sum<<<(N_NODES * 16 + 255) / 256, 256, 0, stream>>>(s2, batch, sums, cnt);
    final_fc<<<(N_GRAPHS + 255) / 256, 256, 0, stream>>>(sums, cnt, Wf, bf, out);
}

// Round 2
// 1041.473 us; speedup vs baseline: 2.8424x; 2.8424x over previous
//
#include <hip/hip_runtime.h>
#include <hip/hip_bf16.h>
#include <math.h>

#define N_NODES 100000
#define N_EDGES 1600000
#define N_GRAPHS 1024

// ---------------- layer 1: node linear (128 -> 64) x4 matrices ----------------
// 16 nodes per block; wave w computes matrix w for all 16 nodes (j-major: W read once/block)
__global__ __launch_bounds__(256) void node_lin1(const float* __restrict__ x,
                          const float* __restrict__ Wq, const float* __restrict__ bq,
                          const float* __restrict__ Wk, const float* __restrict__ bk,
                          const float* __restrict__ Wv, const float* __restrict__ bv,
                          const float* __restrict__ Ws, const float* __restrict__ bs,
                          float* __restrict__ q, float* __restrict__ k,
                          float* __restrict__ v, float* __restrict__ s) {
    __shared__ float xs[16][128];
    int tid = threadIdx.x;
    int nb = blockIdx.x * 16;
    for (int i = tid; i < 16 * 128; i += 256) xs[i >> 7][i & 127] = x[(size_t)nb * 128 + i];
    __syncthreads();
    int w = tid >> 6, t = tid & 63;
    const float* W = (w == 0) ? Wq : (w == 1) ? Wk : (w == 2) ? Wv : Ws;
    const float* b = (w == 0) ? bq : (w == 1) ? bk : (w == 2) ? bv : bs;
    float* out = (w == 0) ? q : (w == 1) ? k : (w == 2) ? v : s;
    float acc[16];
#pragma unroll
    for (int n = 0; n < 16; ++n) acc[n] = 0.f;
#pragma unroll 4
    for (int j = 0; j < 128; ++j) {
        float wv = W[j * 64 + t];
#pragma unroll
        for (int n = 0; n < 16; ++n) acc[n] += xs[n][j] * wv;
    }
    float bb = b[t];
#pragma unroll
    for (int n = 0; n < 16; ++n) out[(size_t)(nb + n) * 64 + t] = acc[n] + bb;
}

// ---------------- layer 1: fused edge pass (score + exp + den + weighted agg) --------
// block = 256 thr = 4 waves; 16 edges/block; wave w owns edges w*4..w*4+3 (64 lanes/edge)
__global__ __launch_bounds__(256) void edge_fused1(const float* __restrict__ ea,
                          const int* __restrict__ ei,
                          const float* __restrict__ q, const float* __restrict__ k,
                          const float* __restrict__ v, const float* __restrict__ We,
                          float* __restrict__ den, float* __restrict__ agg) {
    __shared__ float We_s[32][64];
    __shared__ float ea_s[16][32];
    int tid = threadIdx.x;
    for (int i = tid; i < 32 * 64; i += 256) We_s[i >> 6][i & 63] = We[i];
    int eb = blockIdx.x * 16;
    for (int i = tid; i < 16 * 32; i += 256) ea_s[i >> 5][i & 31] = ea[(size_t)eb * 32 + i];
    __syncthreads();
    int w = tid >> 6, t = tid & 63;
    int el0 = w * 4;
    int srcs[4], dsts[4];
#pragma unroll
    for (int i = 0; i < 4; ++i) {
        int e = eb + el0 + i;
        srcs[i] = ei[e];
        dsts[i] = ei[N_EDGES + e];
    }
    float kv[4], qv[4], vv[4];
#pragma unroll
    for (int i = 0; i < 4; ++i) {
        kv[i] = k[(size_t)srcs[i] * 64 + t];
        qv[i] = q[(size_t)dsts[i] * 64 + t];
        vv[i] = v[(size_t)srcs[i] * 64 + t];
    }
    float et[4] = {0.f, 0.f, 0.f, 0.f};
#pragma unroll 8
    for (int j = 0; j < 32; ++j) {
        float wv = We_s[j][t];
#pragma unroll
        for (int i = 0; i < 4; ++i) et[i] += ea_s[el0 + i][j] * wv;
    }
    float p[4];
#pragma unroll
    for (int i = 0; i < 4; ++i) p[i] = qv[i] * (kv[i] + et[i]);
#pragma unroll
    for (int m = 32; m > 0; m >>= 1) {
#pragma unroll
        for (int i = 0; i < 4; ++i) p[i] += __shfl_xor(p[i], m, 64);
    }
    float a[4];
#pragma unroll
    for (int i = 0; i < 4; ++i) a[i] = __expf(p[i] * 0.125f);
    if (t == 0) {
#pragma unroll
        for (int i = 0; i < 4; ++i) atomicAdd(den + dsts[i], a[i]);
    }
#pragma unroll
    for (int i = 0; i < 4; ++i)
        atomicAdd(agg + (size_t)dsts[i] * 64 + t, a[i] * (vv[i] + et[i]));
}

// ---------------- layer 1 finalize: h = relu(agg/den + skip) ----------------
__global__ void finalize1(const float* __restrict__ agg, const float* __restrict__ den,
                          float* __restrict__ s) {
    int idx = blockIdx.x * blockDim.x + threadIdx.x;
    if (idx >= N_NODES * 64) return;
    int n = idx >> 6;
    float d = den[n] + 1e-16f;
    float r = agg[idx] / d + s[idx];
    s[idx] = r > 0.f ? r : 0.f;
}

// ---------------- layer 2: node linear (64 -> 16) x4 ----------------
// 32 nodes per block; wave w -> matrix w; group g (16 lanes) -> nodes g*8..g*8+7
__global__ __launch_bounds__(256) void node_lin2(const float* __restrict__ h,
                          const float* __restrict__ Wq, const float* __restrict__ bq,
                          const float* __restrict__ Wk, const float* __restrict__ bk,
                          const float* __restrict__ Wv, const float* __restrict__ bv,
                          const float* __restrict__ Ws, const float* __restrict__ bs,
                          float* __restrict__ q, float* __restrict__ k,
                          float* __restrict__ v, float* __restrict__ s) {
    __shared__ float hs[32][65];   // +1 pad: groups read different rows same j
    int tid = threadIdx.x;
    int nb = blockIdx.x * 32;
    for (int i = tid; i < 32 * 64; i += 256) hs[i >> 6][i & 63] = h[(size_t)nb * 64 + i];
    __syncthreads();
    int w = tid >> 6, t = tid & 63, g = t >> 4, c = t & 15;
    const float* W = (w == 0) ? Wq : (w == 1) ? Wk : (w == 2) ? Wv : Ws;
    const float* b = (w == 0) ? bq : (w == 1) ? bk : (w == 2) ? bv : bs;
    float* out = (w == 0) ? q : (w == 1) ? k : (w == 2) ? v : s;
    float acc[8];
#pragma unroll
    for (int n = 0; n < 8; ++n) acc[n] = 0.f;
#pragma unroll 4
    for (int j = 0; j < 64; ++j) {
        float wv = W[j * 16 + c];
#pragma unroll
        for (int n = 0; n < 8; ++n) acc[n] += hs[g * 8 + n][j] * wv;
    }
    float bb = b[c];
#pragma unroll
    for (int n = 0; n < 8; ++n) out[(size_t)(nb + g * 8 + n) * 16 + c] = acc[n] + bb;
}

// ---------------- layer 2: fused edge pass (C=16) ----------------
// block 256 = 4 waves; 64 edges/block; wave w owns 16 edges; 16-lane group g, 4 iters
__global__ __launch_bounds__(256) void edge_fused2(const float* __restrict__ ea,
                          const int* __restrict__ ei,
                          const float* __restrict__ q, const float* __restrict__ k,
                          const float* __restrict__ v, const float* __restrict__ We,
                          float* __restrict__ den, float* __restrict__ agg) {
    __shared__ float We_s[32][16];
    __shared__ float ea_s[64][33];   // +1 pad: 4 groups read different rows same j
    int tid = threadIdx.x;
    for (int i = tid; i < 32 * 16; i += 256) We_s[i >> 4][i & 15] = We[i];
    int eb = blockIdx.x * 64;
    for (int i = tid; i < 64 * 32; i += 256) ea_s[i >> 5][i & 31] = ea[(size_t)eb * 32 + i];
    __syncthreads();
    int w = tid >> 6, t = tid & 63, g = t >> 4, c = t & 15;
    int el0 = w * 16;
    int srcs[4], dsts[4];
#pragma unroll
    for (int i = 0; i < 4; ++i) {
        int e = eb + el0 + i * 4 + g;
        srcs[i] = ei[e];
        dsts[i] = ei[N_EDGES + e];
    }
    float kv[4], qv[4], vv[4];
#pragma unroll
    for (int i = 0; i < 4; ++i) {
        kv[i] = k[(size_t)srcs[i] * 16 + c];
        qv[i] = q[(size_t)dsts[i] * 16 + c];
        vv[i] = v[(size_t)srcs[i] * 16 + c];
    }
    float et[4] = {0.f, 0.f, 0.f, 0.f};
#pragma unroll 8
    for (int j = 0; j < 32; ++j) {
        float wv = We_s[j][c];
#pragma unroll
        for (int i = 0; i < 4; ++i) et[i] += ea_s[el0 + i * 4 + g][j] * wv;
    }
    float p[4];
#pragma unroll
    for (int i = 0; i < 4; ++i) p[i] = qv[i] * (kv[i] + et[i]);
#pragma unroll
    for (int m = 8; m > 0; m >>= 1) {
#pragma unroll
        for (int i = 0; i < 4; ++i) p[i] += __shfl_xor(p[i], m, 64);
    }
    float a[4];
#pragma unroll
    for (int i = 0; i < 4; ++i) a[i] = __expf(p[i] * 0.25f);
    if (c == 0) {
#pragma unroll
        for (int i = 0; i < 4; ++i) atomicAdd(den + dsts[i], a[i]);
    }
#pragma unroll
    for (int i = 0; i < 4; ++i)
        atomicAdd(agg + (size_t)dsts[i] * 16 + c, a[i] * (vv[i] + et[i]));
}

// ---------------- layer 2 finalize ----------------
__global__ void finalize2(const float* __restrict__ agg, const float* __restrict__ den,
                          float* __restrict__ s) {
    int idx = blockIdx.x * blockDim.x + threadIdx.x;
    if (idx >= N_NODES * 16) return;
    int n = idx >> 4;
    float d = den[n] + 1e-16f;
    float r = agg[idx] / d + s[idx];
    s[idx] = r > 0.f ? r : 0.f;
}

// ---------------- pool: atomic sums per graph ----------------
__global__ void pool_sum(const float* __restrict__ h2, const int* __restrict__ batch,
                         float* __restrict__ sums, float* __restrict__ cnt) {
    int idx = blockIdx.x * blockDim.x + threadIdx.x;
    if (idx >= N_NODES * 16) return;
    int n = idx >> 4;
    int c = idx & 15;
    int g = batch[n];
    atomicAdd(sums + g * 16 + c, h2[idx]);
    if (c == 0) atomicAdd(cnt + g, 1.0f);
}

// ---------------- final fc + sigmoid ----------------
__global__ void final_fc(const float* __restrict__ sums, const float* __restrict__ cnt,
                         const float* __restrict__ Wf, const float* __restrict__ bf,
                         float* __restrict__ out) {
    int g = blockIdx.x * blockDim.x + threadIdx.x;
    if (g >= N_GRAPHS) return;
    float cc = cnt[g];
    cc = cc > 1.f ? cc : 1.f;
    float acc = bf[0];
#pragma unroll
    for (int c = 0; c < 16; ++c) acc += (sums[g * 16 + c] / cc) * Wf[c];
    out[g] = 1.f / (1.f + expf(-acc));
}

extern "C" void kernel_launch(void* const* d_in, const int* in_sizes, int n_in,
                              void* d_out, int out_size, void* d_ws, size_t ws_size,
                              hipStream_t stream) {
    const float* x    = (const float*)d_in[0];
    const float* ea   = (const float*)d_in[1];
    const float* Wq1  = (const float*)d_in[2];
    const float* bq1  = (const float*)d_in[3];
    const float* Wk1  = (const float*)d_in[4];
    const float* bk1  = (const float*)d_in[5];
    const float* Wv1  = (const float*)d_in[6];
    const float* bv1  = (const float*)d_in[7];
    const float* We1  = (const float*)d_in[8];
    const float* Ws1  = (const float*)d_in[9];
    const float* bs1  = (const float*)d_in[10];
    const float* Wq2  = (const float*)d_in[11];
    const float* bq2  = (const float*)d_in[12];
    const float* Wk2  = (const float*)d_in[13];
    const float* bk2  = (const float*)d_in[14];
    const float* Wv2  = (const float*)d_in[15];
    const float* bv2  = (const float*)d_in[16];
    const float* We2  = (const float*)d_in[17];
    const float* Ws2  = (const float*)d_in[18];
    const float* bs2  = (const float*)d_in[19];
    const float* Wf   = (const float*)d_in[20];
    const float* bf   = (const float*)d_in[21];
    const int*   ei   = (const int*)d_in[22];
    const int*   batch= (const int*)d_in[23];
    float* out = (float*)d_out;

    // workspace layout (floats)
    float* ws = (float*)d_ws;
    size_t off = 0;
    float* q1   = ws + off; off += (size_t)N_NODES * 64;
    float* k1   = ws + off; off += (size_t)N_NODES * 64;
    float* v1   = ws + off; off += (size_t)N_NODES * 64;
    float* s1   = ws + off; off += (size_t)N_NODES * 64;   // skip; becomes h1 after finalize1
    float* q2   = ws + off; off += (size_t)N_NODES * 16;
    float* k2   = ws + off; off += (size_t)N_NODES * 16;
    float* v2   = ws + off; off += (size_t)N_NODES * 16;
    float* s2   = ws + off; off += (size_t)N_NODES * 16;   // skip; becomes h2
    // ---- contiguous zero block ----
    float* zerop = ws + off;
    float* agg1 = ws + off; off += (size_t)N_NODES * 64;
    float* den1 = ws + off; off += N_NODES;
    float* agg2 = ws + off; off += (size_t)N_NODES * 16;
    float* den2 = ws + off; off += N_NODES;
    float* sums = ws + off; off += (size_t)N_GRAPHS * 16;
    float* cnt  = ws + off; off += N_GRAPHS;
    size_t zero_bytes = ((size_t)N_NODES * 64 + N_NODES + (size_t)N_NODES * 16 + N_NODES +
                         N_GRAPHS * 16 + N_GRAPHS) * sizeof(float);
    hipMemsetAsync(zerop, 0, zero_bytes, stream);

    // ---- layer 1 ----
    node_lin1<<<N_NODES / 16, 256, 0, stream>>>(x, Wq1, bq1, Wk1, bk1, Wv1, bv1, Ws1, bs1,
                                                q1, k1, v1, s1);
    edge_fused1<<<N_EDGES / 16, 256, 0, stream>>>(ea, ei, q1, k1, v1, We1, den1, agg1);
    finalize1<<<(N_NODES * 64 + 255) / 256, 256, 0, stream>>>(agg1, den1, s1);

    // ---- layer 2 (input h1 = s1) ----
    node_lin2<<<N_NODES / 32 + 1, 256, 0, stream>>>(s1, Wq2, bq2, Wk2, bk2, Wv2, bv2, Ws2, bs2,
                                                    q2, k2, v2, s2);
    edge_fused2<<<N_EDGES / 64, 256, 0, stream>>>(ea, ei, q2, k2, v2, We2, den2, agg2);
    finalize2<<<(N_NODES * 16 + 255) / 256, 256, 0, stream>>>(agg2, den2, s2);

    // ---- pool + fc ----
    pool_sum<<<(N_NODES * 16 + 255) / 256, 256, 0, stream>>>(s2, batch, sums, cnt);
    final_fc<<<(N_GRAPHS + 255) / 256, 256, 0, stream>>>(sums, cnt, Wf, bf, out);
}